// Round 16
// baseline (260.273 us; speedup 1.0000x reference)
//
#include <hip/hip_runtime.h>
#include <math.h>

#define NTOK 4096
#define DDIM 1024
#define HDIM 4096
#define NEXP 8
#define BK 64
#define T0MAX 40   // >= NTOK/128 + NEXP-1 live tiles for GEMM0
#define T1MAX 72   // >= NTOK/64  + NEXP-1 live tiles for GEMM1
#define NFILL (NTOK / 256)                            // 16 fill blocks
#define NCVT1 ((HDIM / 64) * (NEXP * (DDIM / 64)))    // 8192 cvt_w1 blocks
#define NG0   ((HDIM / 128) * T0MAX)                  // 1280 gemm0 blocks
#define NCVT2 ((DDIM / 64) * (NEXP * (HDIM / 64)))    // 8192 cvt_w2 blocks

typedef float f32x4 __attribute__((ext_vector_type(4)));
typedef __bf16 bf16x8 __attribute__((ext_vector_type(8)));
typedef const __attribute__((address_space(1))) void gas_t;
typedef __attribute__((address_space(3))) void las_t;

__device__ __forceinline__ unsigned short f2bf(float f) {
    union { float f; unsigned u; } v; v.f = f;
    unsigned u = v.u;
    return (unsigned short)((u + 0x7fffu + ((u >> 16) & 1u)) >> 16);
}

__device__ __forceinline__ float gelu_f(float v) {
    return 0.5f * v * (1.0f + erff(v * 0.70710678118654752f));
}

// ---------------- W tile transpose-convert (device body, LDS passed in) ----------------
// Row-pair reads -> ushort2 LDS writes (8 x ds_write_b32/thread), stride-68 LDS,
// one 16B int4 store per output chunk. (Best-measured cvt geometry: R11/R14; both
// wider-k (R12) and wider-n (R15) variants measured flat-to-worse.)
template<int K, int NC>
__device__ __forceinline__ void cvt_tile(const float* __restrict__ W,
                                         unsigned short* __restrict__ Wt,
                                         int bx, int by, unsigned short* T) {
    constexpr int ktiles = K / 64;
    const int e  = by / ktiles;
    const int k0 = (by % ktiles) * 64;
    const int n0 = bx * 64;
    const float* src = W + (long)e * K * NC + (long)k0 * NC + n0;
    const int tid = threadIdx.x;
#pragma unroll
    for (int i = 0; i < 2; ++i) {
        const int idx = tid + i * 256;           // 0..511 over 32 row-pairs x 16 col-chunks
        const int kp = idx >> 4;                 // row pair 0..31
        const int c4 = (idx & 15) * 4;           // col 0..60
        const float4 v0 = *(const float4*)(src + (long)(2 * kp)     * NC + c4);
        const float4 v1 = *(const float4*)(src + (long)(2 * kp + 1) * NC + c4);
        *(ushort2*)&T[(c4 + 0) * 68 + 2 * kp] = make_ushort2(f2bf(v0.x), f2bf(v1.x));
        *(ushort2*)&T[(c4 + 1) * 68 + 2 * kp] = make_ushort2(f2bf(v0.y), f2bf(v1.y));
        *(ushort2*)&T[(c4 + 2) * 68 + 2 * kp] = make_ushort2(f2bf(v0.z), f2bf(v1.z));
        *(ushort2*)&T[(c4 + 3) * 68 + 2 * kp] = make_ushort2(f2bf(v0.w), f2bf(v1.w));
    }
    __syncthreads();
    unsigned short* dst = Wt + (long)e * NC * K + (long)n0 * K + k0;
#pragma unroll
    for (int i = 0; i < 2; ++i) {
        const int idx = tid + i * 256;           // 0..511 over 64 n-rows x 8 chunks
        const int n = idx >> 3, c8 = (idx & 7) * 8;
        union { ushort4 h[2]; int4 v; } u;
        u.h[0] = *(const ushort4*)&T[n * 68 + c8];
        u.h[1] = *(const ushort4*)&T[n * 68 + c8 + 4];
        *(int4*)(dst + (long)n * K + c8) = u.v;  // 16B coalesced store
    }
}

// ---------------- gating: one wave per token (also emits xb = bf16(x)) ----------------
__global__ void k_gate(const float* __restrict__ x, const float* __restrict__ gw,
                       const float* __restrict__ gb, unsigned short* __restrict__ xb,
                       int* __restrict__ sel, int* __restrict__ counts) {
    const int wid = threadIdx.x >> 6, lane = threadIdx.x & 63;
    const int tok = blockIdx.x * 4 + wid;
    const float4* xr4 = (const float4*)(x + (long)tok * DDIM);
    unsigned short* xbr = xb + (long)tok * DDIM;
    float s[NEXP];
#pragma unroll
    for (int e = 0; e < NEXP; ++e) s[e] = 0.f;
#pragma unroll
    for (int it = 0; it < DDIM / 256; ++it) {
        const int q = it * 64 + lane;            // float4 index
        const float4 xv = xr4[q];
        *(ushort4*)(xbr + q * 4) = make_ushort4(f2bf(xv.x), f2bf(xv.y), f2bf(xv.z), f2bf(xv.w));
#pragma unroll
        for (int j = 0; j < 4; ++j) {
            const float xs = (j == 0) ? xv.x : (j == 1) ? xv.y : (j == 2) ? xv.z : xv.w;
            const float4* g4 = (const float4*)(gw + (long)(q * 4 + j) * NEXP);
            const float4 g0 = g4[0], g1 = g4[1];
            s[0] += xs * g0.x; s[1] += xs * g0.y; s[2] += xs * g0.z; s[3] += xs * g0.w;
            s[4] += xs * g1.x; s[5] += xs * g1.y; s[6] += xs * g1.z; s[7] += xs * g1.w;
        }
    }
#pragma unroll
    for (int e = 0; e < NEXP; ++e)
        for (int off = 32; off > 0; off >>= 1)
            s[e] += __shfl_down(s[e], off);
    if (lane == 0) {
        float best = s[0] + gb[0]; int bi = 0;
#pragma unroll
        for (int e = 1; e < NEXP; ++e) {
            const float v = s[e] + gb[e];
            if (v > best) { best = v; bi = e; }   // strict > keeps lowest index (np.argmax)
        }
        sel[tok] = bi;
        atomicAdd(&counts[bi], 1);
    }
}

// ---------------- fused: fill (blocks 0..NFILL-1, LDS-rank) + cvt(w1) behind ----------
// fill: per-block LDS histogram + rank; ONE global atomic per (block,expert) = 128
// total. cvt: W1t transpose stream.
__global__ __launch_bounds__(256) void k_fillcvt(
        const int* __restrict__ sel, const int* __restrict__ counts,
        int* __restrict__ cur, int* __restrict__ offs,
        int* __restrict__ list, int* __restrict__ t0,
        int* __restrict__ t1, float* __restrict__ laux,
        const float* __restrict__ w1, unsigned short* __restrict__ W1t) {
    __shared__ unsigned short T[64 * 68];
    __shared__ int hist[NEXP], basep[NEXP];
    const int bid = blockIdx.x;
    if (bid >= NFILL) {
        const int cv = bid - NFILL;
        cvt_tile<DDIM, HDIM>(w1, W1t, cv % (HDIM / 64), cv / (HDIM / 64), T);
        return;
    }
    const int tid = threadIdx.x;
    const int t = bid * 256 + tid;               // 16*256 == NTOK exactly
    const int e = sel[t];
    if (tid < NEXP) hist[tid] = 0;
    __syncthreads();
    const int rank = atomicAdd(&hist[e], 1);     // LDS atomic: block-local rank
    __syncthreads();
    if (tid < NEXP) {
        int off_e = 0;
#pragma unroll
        for (int j = 0; j < NEXP; ++j) off_e += (j < tid) ? counts[j] : 0;
        basep[tid] = off_e + atomicAdd(&cur[tid], hist[tid]);   // grab block's span
    }
    __syncthreads();
    list[basep[e] + rank] = t;
    if (t == 0) {
        int o = 0;
        for (int ee = 0; ee < NEXP; ++ee) { offs[ee] = o; o += counts[ee]; }
        offs[NEXP] = o;
        int i0 = 0;
        for (int ee = 0; ee < NEXP; ++ee)
            for (int m = 0; m < counts[ee]; m += 128) t0[i0++] = (ee << 16) | m;
        while (i0 < T0MAX) t0[i0++] = -1;
        int i1 = 0;
        for (int ee = 0; ee < NEXP; ++ee)
            for (int m = 0; m < counts[ee]; m += 64) t1[i1++] = (ee << 16) | m;
        while (i1 < T1MAX) t1[i1++] = -1;
        laux[0] = 0.f;
    }
}

// ---------------- standalone transpose-convert kernel (small-ws fallback) -------------
template<int K, int NC>
__global__ __launch_bounds__(256) void k_cvt_w(const float* __restrict__ W,
                                               unsigned short* __restrict__ Wt) {
    __shared__ unsigned short T[64 * 68];
    cvt_tile<K, NC>(W, Wt, blockIdx.x, blockIdx.y, T);
}

// ---------------- grouped GEMM: R5 single-buffer structure + compact grid -------------
// 256 thr = 4 waves, per-wave (BM/2)x(BN/2). Single-buffered LDS (best-measured GEMM
// variant), XOR swizzle via pre-swizzled global source, global_load_lds w=16, compact
// ttab grid. FUSE adds cvt_w2 blocks (IDs >= NG0): compute-bound gemm host + BW-bound
// cvt guest = the fusion combination that measured WELL (flag-based intra-dispatch
// dependencies measured 6x WORSE in R13 -- do not reintroduce).
template<int MODE, int BM_, int BN_, bool FUSE>
__global__ __launch_bounds__(256) void k_gemm(
        const unsigned short* __restrict__ Ain,
        const unsigned short* __restrict__ Wt,
        const float* __restrict__ bias,
        unsigned short* __restrict__ Hout, float* __restrict__ Yout,
        const int* __restrict__ counts, const int* __restrict__ offs,
        const int* __restrict__ list, const int* __restrict__ ttab,
        const float* __restrict__ Wcvt, unsigned short* __restrict__ Wtcvt) {
    static_assert(BM_ % 32 == 0 && BN_ % 32 == 0, "tile");
    constexpr int K    = (MODE == 0) ? DDIM : HDIM;
    constexpr int NC   = (MODE == 0) ? HDIM : DDIM;
    constexpr int NT   = K / BK;
    constexpr int FM   = BM_ / 32;
    constexpr int FN   = BN_ / 32;
    constexpr int LA   = BM_ / 32;   // A loads per thread per tile
    constexpr int LB   = BN_ / 32;
    constexpr int EP   = 136;        // MODE0 epilogue stride (shorts), 16B-mult
    constexpr int STAGE_SH = BM_ * 64 + BN_ * 64;
    constexpr int SH_SZ = (MODE == 0 && BM_ * EP > STAGE_SH) ? BM_ * EP : STAGE_SH;

    __shared__ __align__(16) unsigned short sh[SH_SZ];

    int bx, by;
    if constexpr (FUSE) {
        const int bid = blockIdx.x;
        if (bid >= NG0) {                         // cvt_w2 block
            const int cv = bid - NG0;
            cvt_tile<HDIM, DDIM>(Wcvt, Wtcvt, cv % (DDIM / 64), cv / (DDIM / 64), sh);
            return;
        }
        bx = bid % (NC / BN_); by = bid / (NC / BN_);
    } else {
        bx = blockIdx.x; by = blockIdx.y;
    }

    const int code = ttab[by];
    if (code < 0) return;
    const int e  = code >> 16;
    const int m0 = code & 0xFFFF;
    const int cnt  = counts[e];
    const int base = offs[e];
    const int n0   = bx * BN_;

    unsigned short* Asb = sh;
    unsigned short* Btb = sh + BM_ * 64;

    const int tid  = threadIdx.x;
    const int lane = tid & 63, wid = tid >> 6;
    const int lr = lane >> 3, lc = lane & 7;
    const int sb = (lc * 16) ^ (lr << 4);        // pre-swizzled source byte offset

    const unsigned short* pA[LA];
#pragma unroll
    for (int i = 0; i < LA; ++i) {
        const int r = wid * (BM_ / 4) + i * 8 + lr;
        int rr = m0 + r; if (rr >= cnt) rr = cnt - 1;
        const long grow = (MODE == 0) ? (long)list[base + rr] : (long)(base + rr);
        pA[i] = (const unsigned short*)((const char*)(Ain + grow * K) + sb);
    }
    const unsigned short* We = Wt + (long)e * NC * K;
    const unsigned short* pB[LB];
#pragma unroll
    for (int i = 0; i < LB; ++i) {
        const int r = wid * (BN_ / 4) + i * 8 + lr;
        pB[i] = (const unsigned short*)((const char*)(We + (long)(n0 + r) * K) + sb);
    }

    const int wm = (wid >> 1) * (BM_ / 2);
    const int wn = (wid & 1) * (BN_ / 2);
    const int hk = 16 * (lane >> 4);

    const f32x4 zero4 = {0.f, 0.f, 0.f, 0.f};
    f32x4 acc[FM][FN];
#pragma unroll
    for (int i = 0; i < FM; ++i)
#pragma unroll
        for (int j = 0; j < FN; ++j) acc[i][j] = zero4;

    for (int t = 0; t < NT; ++t) {
        __syncthreads();   // prior-iter readers done
#pragma unroll
        for (int i = 0; i < LA; ++i)
            __builtin_amdgcn_global_load_lds((gas_t*)(pA[i] + t * 64),
                (las_t*)(Asb + (wid * (BM_ / 4) + i * 8) * 64), 16, 0, 0);
#pragma unroll
        for (int i = 0; i < LB; ++i)
            __builtin_amdgcn_global_load_lds((gas_t*)(pB[i] + t * 64),
                (las_t*)(Btb + (wid * (BN_ / 4) + i * 8) * 64), 16, 0, 0);
        __syncthreads();   // staging complete
#pragma unroll
        for (int kk = 0; kk < BK; kk += 32) {
            bf16x8 a[FM], b[FN];
#pragma unroll
            for (int mf = 0; mf < FM; ++mf) {
                const int r  = wm + mf * 16 + (lane & 15);
                const int kb = (2 * kk + hk) ^ ((r & 7) << 4);
                a[mf] = *(const bf16x8*)((const char*)Asb + r * 128 + kb);
            }
#pragma unroll
            for (int nf = 0; nf < FN; ++nf) {
                const int cc = wn + nf * 16 + (lane & 15);
                const int kb = (2 * kk + hk) ^ ((cc & 7) << 4);
                b[nf] = *(const bf16x8*)((const char*)Btb + cc * 128 + kb);
            }
            __builtin_amdgcn_s_setprio(1);
#pragma unroll
            for (int mf = 0; mf < FM; ++mf)
#pragma unroll
                for (int nf = 0; nf < FN; ++nf)
                    acc[mf][nf] = __builtin_amdgcn_mfma_f32_16x16x32_bf16(
                        a[mf], b[nf], acc[mf][nf], 0, 0, 0);
            __builtin_amdgcn_s_setprio(0);
        }
    }

    // ---- epilogue ----
    if constexpr (MODE == 0) {
        // bias+gelu -> bf16 tile in LDS ([BM][EP=136] shorts, 272B rows, 16B-aligned),
        // then 16B coalesced stores: thread -> (row = tid>>1, 64-col half).
        __syncthreads();   // all MFMA reads of sh done
#pragma unroll
        for (int nf = 0; nf < FN; ++nf) {
            const int cl = wn + nf * 16 + (lane & 15);
            const float bv = bias[(long)e * NC + n0 + cl];
#pragma unroll
            for (int mf = 0; mf < FM; ++mf) {
#pragma unroll
                for (int ri = 0; ri < 4; ++ri) {
                    const int rl = wm + mf * 16 + (lane >> 4) * 4 + ri;
                    sh[rl * EP + cl] = f2bf(gelu_f(acc[mf][nf][ri] + bv));
                }
            }
        }
        __syncthreads();
        const int row = tid >> 1, ch = (tid & 1) * 64;
        if (m0 + row < cnt) {
            char* dst = (char*)(Hout + (long)(base + m0 + row) * HDIM + n0 + ch);
            const char* srcp = (const char*)sh + row * (EP * 2) + ch * 2;
#pragma unroll
            for (int j = 0; j < 4; ++j) {
                const int4 v0 = *(const int4*)(srcp + j * 32);
                const int4 v1 = *(const int4*)(srcp + j * 32 + 16);
                *(int4*)(dst + j * 32)      = v0;
                *(int4*)(dst + j * 32 + 16) = v1;
            }
        }
    } else {
#pragma unroll
        for (int nf = 0; nf < FN; ++nf) {
            const int coln = n0 + wn + nf * 16 + (lane & 15);
            const float bv = bias[(long)e * NC + coln];
#pragma unroll
            for (int mf = 0; mf < FM; ++mf) {
                const int rb = m0 + wm + mf * 16 + (lane >> 4) * 4;
#pragma unroll
                for (int ri = 0; ri < 4; ++ri) {
                    const int row = rb + ri;
                    if (row < cnt)
                        Yout[(long)list[base + row] * DDIM + coln] = acc[mf][nf][ri] + bv;
                }
            }
        }
    }
}

extern "C" void kernel_launch(void* const* d_in, const int* in_sizes, int n_in,
                              void* d_out, int out_size, void* d_ws, size_t ws_size,
                              hipStream_t stream) {
    const float* x      = (const float*)d_in[0];
    const float* gate_w = (const float*)d_in[1];
    const float* gate_b = (const float*)d_in[2];
    const float* w1     = (const float*)d_in[3];
    const float* b1     = (const float*)d_in[4];
    const float* w2     = (const float*)d_in[5];
    const float* b2     = (const float*)d_in[6];
    float* out = (float*)d_out;

    // workspace layout
    char* ws = (char*)d_ws;
    int* counts  = (int*)(ws);                 // 8
    int* cur     = (int*)(ws + 128);           // 8
    int* offs    = (int*)(ws + 256);           // 9
    int* t0      = (int*)(ws + 512);           // T0MAX
    int* t1      = (int*)(ws + 768);           // T1MAX
    int* sel     = (int*)(ws + 4096);          // 4096
    int* list    = (int*)(ws + 20480);         // 4096
    unsigned short* xb  = (unsigned short*)(ws + 65536);                      // 8 MB
    unsigned short* Hws = (unsigned short*)(ws + 65536 + 8388608);            // 33.5 MB
    unsigned short* W1t = (unsigned short*)(ws + 65536 + 8388608 + 33554432); // 64 MB
    unsigned short* W2s = W1t + (size_t)NEXP * HDIM * DDIM;                   // 64 MB (big path)
    const size_t WS_SMALL = 65536 + 8388608 + 33554432 + 67108864;
    const size_t WS_BIG   = WS_SMALL + 67108864;
    if (ws_size < WS_SMALL) return;  // deterministic fail, no corruption
    const bool big = ws_size >= WS_BIG;
    unsigned short* W2t = big ? W2s : W1t;     // small path reuses W1t region sequentially

    hipMemsetAsync(ws, 0, 256, stream);   // counts + cur

    // gate (+ xb): standalone (gate+cvt fusion measured 2x WORSE than sequential)
    k_gate<<<NTOK / 4, 256, 0, stream>>>(x, gate_w, gate_b, xb, sel, counts);

    // fill (16 LDS-rank blocks) fused ahead of cvt(w1) -> W1t
    k_fillcvt<<<NFILL + NCVT1, 256, 0, stream>>>(sel, counts, cur, offs, list, t0, t1,
                                                 out + (long)NTOK * DDIM, w1, W1t);

    if (big) {
        // FFN up+gelu FUSED with cvt(w2)->W2t: gemm blocks 0..NG0-1, cvt blocks behind
        k_gemm<0, 128, 128, true><<<NG0 + NCVT2, 256, 0, stream>>>(
            xb, W1t, b1, Hws, nullptr, counts, offs, list, t0, w2, W2t);
    } else {
        k_gemm<0, 128, 128, false><<<dim3(HDIM / 128, T0MAX), 256, 0, stream>>>(
            xb, W1t, b1, Hws, nullptr, counts, offs, list, t0, nullptr, nullptr);
        k_cvt_w<HDIM, DDIM><<<dim3(DDIM / 64, NEXP * (HDIM / 64)), 256, 0, stream>>>(w2, W2t);
    }

    // FFN down: 64x128 tiles (best-measured GEMM1), compact grid
    k_gemm<1, 64, 128, false><<<dim3(DDIM / 128, T1MAX), 256, 0, stream>>>(
        Hws, W2t, b2, nullptr, out, counts, offs, list, t1, nullptr, nullptr);
}

// Round 17
// 255.128 us; speedup vs baseline: 1.0202x; 1.0202x over previous
//
#include <hip/hip_runtime.h>
#include <math.h>

#define NTOK 4096
#define DDIM 1024
#define HDIM 4096
#define NEXP 8
#define BK 64
#define T0MAX 40   // >= NTOK/128 + NEXP-1 live tiles for GEMM0
#define T1MAX 72   // >= NTOK/64  + NEXP-1 live tiles for GEMM1
#define NFILL (NTOK / 256)                            // 16 fill blocks
#define NCVT1 ((HDIM / 64) * (NEXP * (DDIM / 64)))    // 8192 cvt_w1 blocks
#define NG0   ((HDIM / 128) * T0MAX)                  // 1280 gemm0 blocks
#define NCVT2 ((DDIM / 64) * (NEXP * (HDIM / 64)))    // 8192 cvt_w2 blocks

typedef float f32x4 __attribute__((ext_vector_type(4)));
typedef __bf16 bf16x8 __attribute__((ext_vector_type(8)));
typedef const __attribute__((address_space(1))) void gas_t;
typedef __attribute__((address_space(3))) void las_t;

__device__ __forceinline__ unsigned short f2bf(float f) {
    union { float f; unsigned u; } v; v.f = f;
    unsigned u = v.u;
    return (unsigned short)((u + 0x7fffu + ((u >> 16) & 1u)) >> 16);
}

__device__ __forceinline__ float gelu_f(float v) {
    return 0.5f * v * (1.0f + erff(v * 0.70710678118654752f));
}

// ---------------- W tile transpose-convert (device body, LDS passed in) ----------------
// Row-pair reads -> ushort2 LDS writes (8 x ds_write_b32/thread), stride-68 LDS,
// one 16B int4 store per output chunk. (Best-measured cvt geometry: R11/R14; both
// wider-k (R12) and wider-n (R15) variants measured flat-to-worse.)
template<int K, int NC>
__device__ __forceinline__ void cvt_tile(const float* __restrict__ W,
                                         unsigned short* __restrict__ Wt,
                                         int bx, int by, unsigned short* T) {
    constexpr int ktiles = K / 64;
    const int e  = by / ktiles;
    const int k0 = (by % ktiles) * 64;
    const int n0 = bx * 64;
    const float* src = W + (long)e * K * NC + (long)k0 * NC + n0;
    const int tid = threadIdx.x;
#pragma unroll
    for (int i = 0; i < 2; ++i) {
        const int idx = tid + i * 256;           // 0..511 over 32 row-pairs x 16 col-chunks
        const int kp = idx >> 4;                 // row pair 0..31
        const int c4 = (idx & 15) * 4;           // col 0..60
        const float4 v0 = *(const float4*)(src + (long)(2 * kp)     * NC + c4);
        const float4 v1 = *(const float4*)(src + (long)(2 * kp + 1) * NC + c4);
        *(ushort2*)&T[(c4 + 0) * 68 + 2 * kp] = make_ushort2(f2bf(v0.x), f2bf(v1.x));
        *(ushort2*)&T[(c4 + 1) * 68 + 2 * kp] = make_ushort2(f2bf(v0.y), f2bf(v1.y));
        *(ushort2*)&T[(c4 + 2) * 68 + 2 * kp] = make_ushort2(f2bf(v0.z), f2bf(v1.z));
        *(ushort2*)&T[(c4 + 3) * 68 + 2 * kp] = make_ushort2(f2bf(v0.w), f2bf(v1.w));
    }
    __syncthreads();
    unsigned short* dst = Wt + (long)e * NC * K + (long)n0 * K + k0;
#pragma unroll
    for (int i = 0; i < 2; ++i) {
        const int idx = tid + i * 256;           // 0..511 over 64 n-rows x 8 chunks
        const int n = idx >> 3, c8 = (idx & 7) * 8;
        union { ushort4 h[2]; int4 v; } u;
        u.h[0] = *(const ushort4*)&T[n * 68 + c8];
        u.h[1] = *(const ushort4*)&T[n * 68 + c8 + 4];
        *(int4*)(dst + (long)n * K + c8) = u.v;  // 16B coalesced store
    }
}

// ---------------- gating: one wave per token (also emits xb = bf16(x)) ----------------
__global__ void k_gate(const float* __restrict__ x, const float* __restrict__ gw,
                       const float* __restrict__ gb, unsigned short* __restrict__ xb,
                       int* __restrict__ sel, int* __restrict__ counts) {
    const int wid = threadIdx.x >> 6, lane = threadIdx.x & 63;
    const int tok = blockIdx.x * 4 + wid;
    const float4* xr4 = (const float4*)(x + (long)tok * DDIM);
    unsigned short* xbr = xb + (long)tok * DDIM;
    float s[NEXP];
#pragma unroll
    for (int e = 0; e < NEXP; ++e) s[e] = 0.f;
#pragma unroll
    for (int it = 0; it < DDIM / 256; ++it) {
        const int q = it * 64 + lane;            // float4 index
        const float4 xv = xr4[q];
        *(ushort4*)(xbr + q * 4) = make_ushort4(f2bf(xv.x), f2bf(xv.y), f2bf(xv.z), f2bf(xv.w));
#pragma unroll
        for (int j = 0; j < 4; ++j) {
            const float xs = (j == 0) ? xv.x : (j == 1) ? xv.y : (j == 2) ? xv.z : xv.w;
            const float4* g4 = (const float4*)(gw + (long)(q * 4 + j) * NEXP);
            const float4 g0 = g4[0], g1 = g4[1];
            s[0] += xs * g0.x; s[1] += xs * g0.y; s[2] += xs * g0.z; s[3] += xs * g0.w;
            s[4] += xs * g1.x; s[5] += xs * g1.y; s[6] += xs * g1.z; s[7] += xs * g1.w;
        }
    }
#pragma unroll
    for (int e = 0; e < NEXP; ++e)
        for (int off = 32; off > 0; off >>= 1)
            s[e] += __shfl_down(s[e], off);
    if (lane == 0) {
        float best = s[0] + gb[0]; int bi = 0;
#pragma unroll
        for (int e = 1; e < NEXP; ++e) {
            const float v = s[e] + gb[e];
            if (v > best) { best = v; bi = e; }   // strict > keeps lowest index (np.argmax)
        }
        sel[tok] = bi;
        atomicAdd(&counts[bi], 1);
    }
}

// ---------------- fused: fill (blocks 0..NFILL-1, LDS-rank) + cvt(w1) behind ----------
// fill: per-block LDS histogram + rank; ONE global atomic per (block,expert) = 128
// total. cvt: W1t transpose stream.
__global__ __launch_bounds__(256) void k_fillcvt(
        const int* __restrict__ sel, const int* __restrict__ counts,
        int* __restrict__ cur, int* __restrict__ offs,
        int* __restrict__ list, int* __restrict__ t0,
        int* __restrict__ t1, float* __restrict__ laux,
        const float* __restrict__ w1, unsigned short* __restrict__ W1t) {
    __shared__ unsigned short T[64 * 68];
    __shared__ int hist[NEXP], basep[NEXP];
    const int bid = blockIdx.x;
    if (bid >= NFILL) {
        const int cv = bid - NFILL;
        cvt_tile<DDIM, HDIM>(w1, W1t, cv % (HDIM / 64), cv / (HDIM / 64), T);
        return;
    }
    const int tid = threadIdx.x;
    const int t = bid * 256 + tid;               // 16*256 == NTOK exactly
    const int e = sel[t];
    if (tid < NEXP) hist[tid] = 0;
    __syncthreads();
    const int rank = atomicAdd(&hist[e], 1);     // LDS atomic: block-local rank
    __syncthreads();
    if (tid < NEXP) {
        int off_e = 0;
#pragma unroll
        for (int j = 0; j < NEXP; ++j) off_e += (j < tid) ? counts[j] : 0;
        basep[tid] = off_e + atomicAdd(&cur[tid], hist[tid]);   // grab block's span
    }
    __syncthreads();
    list[basep[e] + rank] = t;
    if (t == 0) {
        int o = 0;
        for (int ee = 0; ee < NEXP; ++ee) { offs[ee] = o; o += counts[ee]; }
        offs[NEXP] = o;
        int i0 = 0;
        for (int ee = 0; ee < NEXP; ++ee)
            for (int m = 0; m < counts[ee]; m += 128) t0[i0++] = (ee << 16) | m;
        while (i0 < T0MAX) t0[i0++] = -1;
        int i1 = 0;
        for (int ee = 0; ee < NEXP; ++ee)
            for (int m = 0; m < counts[ee]; m += 64) t1[i1++] = (ee << 16) | m;
        while (i1 < T1MAX) t1[i1++] = -1;
        laux[0] = 0.f;
    }
}

// ---------------- standalone transpose-convert kernel (small-ws fallback) -------------
template<int K, int NC>
__global__ __launch_bounds__(256) void k_cvt_w(const float* __restrict__ W,
                                               unsigned short* __restrict__ Wt) {
    __shared__ unsigned short T[64 * 68];
    cvt_tile<K, NC>(W, Wt, blockIdx.x, blockIdx.y, T);
}

// ---------------- grouped GEMM: R5 single-buffer structure + compact grid -------------
// 256 thr = 4 waves, per-wave (BM/2)x(BN/2). Single-buffered LDS (best-measured GEMM
// variant), XOR swizzle via pre-swizzled global source, global_load_lds w=16, compact
// ttab grid. FUSE adds cvt_w2 blocks (IDs >= NG0): compute-bound gemm host + BW-bound
// cvt guest = the fusion combination that measured WELL (flag-based intra-dispatch
// dependencies measured 6x WORSE in R13 -- do not reintroduce).
template<int MODE, int BM_, int BN_, bool FUSE>
__global__ __launch_bounds__(256) void k_gemm(
        const unsigned short* __restrict__ Ain,
        const unsigned short* __restrict__ Wt,
        const float* __restrict__ bias,
        unsigned short* __restrict__ Hout, float* __restrict__ Yout,
        const int* __restrict__ counts, const int* __restrict__ offs,
        const int* __restrict__ list, const int* __restrict__ ttab,
        const float* __restrict__ Wcvt, unsigned short* __restrict__ Wtcvt) {
    static_assert(BM_ % 32 == 0 && BN_ % 32 == 0, "tile");
    constexpr int K    = (MODE == 0) ? DDIM : HDIM;
    constexpr int NC   = (MODE == 0) ? HDIM : DDIM;
    constexpr int NT   = K / BK;
    constexpr int FM   = BM_ / 32;
    constexpr int FN   = BN_ / 32;
    constexpr int LA   = BM_ / 32;   // A loads per thread per tile
    constexpr int LB   = BN_ / 32;
    constexpr int EP   = 136;        // MODE0 epilogue stride (shorts), 16B-mult
    constexpr int STAGE_SH = BM_ * 64 + BN_ * 64;
    constexpr int SH_SZ = (MODE == 0 && BM_ * EP > STAGE_SH) ? BM_ * EP : STAGE_SH;

    __shared__ __align__(16) unsigned short sh[SH_SZ];

    int bx, by;
    if constexpr (FUSE) {
        const int bid = blockIdx.x;
        if (bid >= NG0) {                         // cvt_w2 block
            const int cv = bid - NG0;
            cvt_tile<HDIM, DDIM>(Wcvt, Wtcvt, cv % (DDIM / 64), cv / (DDIM / 64), sh);
            return;
        }
        bx = bid % (NC / BN_); by = bid / (NC / BN_);
    } else {
        bx = blockIdx.x; by = blockIdx.y;
    }

    const int code = ttab[by];
    if (code < 0) return;
    const int e  = code >> 16;
    const int m0 = code & 0xFFFF;
    const int cnt  = counts[e];
    const int base = offs[e];
    const int n0   = bx * BN_;

    unsigned short* Asb = sh;
    unsigned short* Btb = sh + BM_ * 64;

    const int tid  = threadIdx.x;
    const int lane = tid & 63, wid = tid >> 6;
    const int lr = lane >> 3, lc = lane & 7;
    const int sb = (lc * 16) ^ (lr << 4);        // pre-swizzled source byte offset

    const unsigned short* pA[LA];
#pragma unroll
    for (int i = 0; i < LA; ++i) {
        const int r = wid * (BM_ / 4) + i * 8 + lr;
        int rr = m0 + r; if (rr >= cnt) rr = cnt - 1;
        const long grow = (MODE == 0) ? (long)list[base + rr] : (long)(base + rr);
        pA[i] = (const unsigned short*)((const char*)(Ain + grow * K) + sb);
    }
    const unsigned short* We = Wt + (long)e * NC * K;
    const unsigned short* pB[LB];
#pragma unroll
    for (int i = 0; i < LB; ++i) {
        const int r = wid * (BN_ / 4) + i * 8 + lr;
        pB[i] = (const unsigned short*)((const char*)(We + (long)(n0 + r) * K) + sb);
    }

    const int wm = (wid >> 1) * (BM_ / 2);
    const int wn = (wid & 1) * (BN_ / 2);
    const int hk = 16 * (lane >> 4);

    const f32x4 zero4 = {0.f, 0.f, 0.f, 0.f};
    f32x4 acc[FM][FN];
#pragma unroll
    for (int i = 0; i < FM; ++i)
#pragma unroll
        for (int j = 0; j < FN; ++j) acc[i][j] = zero4;

    for (int t = 0; t < NT; ++t) {
        __syncthreads();   // prior-iter readers done
#pragma unroll
        for (int i = 0; i < LA; ++i)
            __builtin_amdgcn_global_load_lds((gas_t*)(pA[i] + t * 64),
                (las_t*)(Asb + (wid * (BM_ / 4) + i * 8) * 64), 16, 0, 0);
#pragma unroll
        for (int i = 0; i < LB; ++i)
            __builtin_amdgcn_global_load_lds((gas_t*)(pB[i] + t * 64),
                (las_t*)(Btb + (wid * (BN_ / 4) + i * 8) * 64), 16, 0, 0);
        __syncthreads();   // staging complete
#pragma unroll
        for (int kk = 0; kk < BK; kk += 32) {
            bf16x8 a[FM], b[FN];
#pragma unroll
            for (int mf = 0; mf < FM; ++mf) {
                const int r  = wm + mf * 16 + (lane & 15);
                const int kb = (2 * kk + hk) ^ ((r & 7) << 4);
                a[mf] = *(const bf16x8*)((const char*)Asb + r * 128 + kb);
            }
#pragma unroll
            for (int nf = 0; nf < FN; ++nf) {
                const int cc = wn + nf * 16 + (lane & 15);
                const int kb = (2 * kk + hk) ^ ((cc & 7) << 4);
                b[nf] = *(const bf16x8*)((const char*)Btb + cc * 128 + kb);
            }
            __builtin_amdgcn_s_setprio(1);
#pragma unroll
            for (int mf = 0; mf < FM; ++mf)
#pragma unroll
                for (int nf = 0; nf < FN; ++nf)
                    acc[mf][nf] = __builtin_amdgcn_mfma_f32_16x16x32_bf16(
                        a[mf], b[nf], acc[mf][nf], 0, 0, 0);
            __builtin_amdgcn_s_setprio(0);
        }
    }

    // ---- epilogue ----
    if constexpr (MODE == 0) {
        // bias+gelu -> bf16 tile in LDS ([BM][EP=136] shorts, 272B rows, 16B-aligned),
        // then 16B coalesced stores: thread -> (row = tid>>1, 64-col half).
        __syncthreads();   // all MFMA reads of sh done
#pragma unroll
        for (int nf = 0; nf < FN; ++nf) {
            const int cl = wn + nf * 16 + (lane & 15);
            const float bv = bias[(long)e * NC + n0 + cl];
#pragma unroll
            for (int mf = 0; mf < FM; ++mf) {
#pragma unroll
                for (int ri = 0; ri < 4; ++ri) {
                    const int rl = wm + mf * 16 + (lane >> 4) * 4 + ri;
                    sh[rl * EP + cl] = f2bf(gelu_f(acc[mf][nf][ri] + bv));
                }
            }
        }
        __syncthreads();
        const int row = tid >> 1, ch = (tid & 1) * 64;
        if (m0 + row < cnt) {
            char* dst = (char*)(Hout + (long)(base + m0 + row) * HDIM + n0 + ch);
            const char* srcp = (const char*)sh + row * (EP * 2) + ch * 2;
#pragma unroll
            for (int j = 0; j < 4; ++j) {
                const int4 v0 = *(const int4*)(srcp + j * 32);
                const int4 v1 = *(const int4*)(srcp + j * 32 + 16);
                *(int4*)(dst + j * 32)      = v0;
                *(int4*)(dst + j * 32 + 16) = v1;
            }
        }
    } else {
#pragma unroll
        for (int nf = 0; nf < FN; ++nf) {
            const int coln = n0 + wn + nf * 16 + (lane & 15);
            const float bv = bias[(long)e * NC + coln];
#pragma unroll
            for (int mf = 0; mf < FM; ++mf) {
                const int rb = m0 + wm + mf * 16 + (lane >> 4) * 4;
#pragma unroll
                for (int ri = 0; ri < 4; ++ri) {
                    const int row = rb + ri;
                    if (row < cnt)
                        Yout[(long)list[base + row] * DDIM + coln] = acc[mf][nf][ri] + bv;
                }
            }
        }
    }
}

extern "C" void kernel_launch(void* const* d_in, const int* in_sizes, int n_in,
                              void* d_out, int out_size, void* d_ws, size_t ws_size,
                              hipStream_t stream) {
    const float* x      = (const float*)d_in[0];
    const float* gate_w = (const float*)d_in[1];
    const float* gate_b = (const float*)d_in[2];
    const float* w1     = (const float*)d_in[3];
    const float* b1     = (const float*)d_in[4];
    const float* w2     = (const float*)d_in[5];
    const float* b2     = (const float*)d_in[6];
    float* out = (float*)d_out;

    // workspace layout
    char* ws = (char*)d_ws;
    int* counts  = (int*)(ws);                 // 8
    int* cur     = (int*)(ws + 128);           // 8
    int* offs    = (int*)(ws + 256);           // 9
    int* t0      = (int*)(ws + 512);           // T0MAX
    int* t1      = (int*)(ws + 768);           // T1MAX
    int* sel     = (int*)(ws + 4096);          // 4096
    int* list    = (int*)(ws + 20480);         // 4096
    unsigned short* xb  = (unsigned short*)(ws + 65536);                      // 8 MB
    unsigned short* Hws = (unsigned short*)(ws + 65536 + 8388608);            // 33.5 MB
    unsigned short* W1t = (unsigned short*)(ws + 65536 + 8388608 + 33554432); // 64 MB
    unsigned short* W2s = W1t + (size_t)NEXP * HDIM * DDIM;                   // 64 MB (big path)
    const size_t WS_SMALL = 65536 + 8388608 + 33554432 + 67108864;
    const size_t WS_BIG   = WS_SMALL + 67108864;
    if (ws_size < WS_SMALL) return;  // deterministic fail, no corruption
    const bool big = ws_size >= WS_BIG;
    unsigned short* W2t = big ? W2s : W1t;     // small path reuses W1t region sequentially

    hipMemsetAsync(ws, 0, 256, stream);   // counts + cur

    // gate (+ xb): standalone (gate+cvt fusion measured 2x WORSE than sequential)
    k_gate<<<NTOK / 4, 256, 0, stream>>>(x, gate_w, gate_b, xb, sel, counts);

    // fill (16 LDS-rank blocks) fused ahead of cvt(w1) -> W1t
    k_fillcvt<<<NFILL + NCVT1, 256, 0, stream>>>(sel, counts, cur, offs, list, t0, t1,
                                                 out + (long)NTOK * DDIM, w1, W1t);

    if (big) {
        // FFN up+gelu FUSED with cvt(w2)->W2t: gemm blocks 0..NG0-1, cvt blocks behind
        k_gemm<0, 128, 128, true><<<NG0 + NCVT2, 256, 0, stream>>>(
            xb, W1t, b1, Hws, nullptr, counts, offs, list, t0, w2, W2t);
    } else {
        k_gemm<0, 128, 128, false><<<dim3(HDIM / 128, T0MAX), 256, 0, stream>>>(
            xb, W1t, b1, Hws, nullptr, counts, offs, list, t0, nullptr, nullptr);
        k_cvt_w<HDIM, DDIM><<<dim3(DDIM / 64, NEXP * (HDIM / 64)), 256, 0, stream>>>(w2, W2t);
    }

    // FFN down: 64x128 tiles (best-measured GEMM1), compact grid
    k_gemm<1, 64, 128, false><<<dim3(DDIM / 128, T1MAX), 256, 0, stream>>>(
        Hws, W2t, b2, nullptr, out, counts, offs, list, t1, nullptr, nullptr);
}

// Round 18
// 249.909 us; speedup vs baseline: 1.0415x; 1.0209x over previous
//
#include <hip/hip_runtime.h>
#include <math.h>

#define NTOK 4096
#define DDIM 1024
#define HDIM 4096
#define NEXP 8
#define BK 64
#define T0MAX 40   // >= NTOK/128 + NEXP-1 live tiles for GEMM0
#define T1MAX 72   // >= NTOK/64  + NEXP-1 live tiles for GEMM1
#define NFILL (NTOK / 256)                            // 16 fill blocks
#define NCVT1 ((HDIM / 64) * (NEXP * (DDIM / 64)))    // 8192 cvt_w1 blocks
#define NG0   ((HDIM / 128) * T0MAX)                  // 1280 gemm0 blocks
#define NCVT2 ((DDIM / 64) * (NEXP * (HDIM / 64)))    // 8192 cvt_w2 blocks

typedef float f32x4 __attribute__((ext_vector_type(4)));
typedef __bf16 bf16x8 __attribute__((ext_vector_type(8)));
typedef const __attribute__((address_space(1))) void gas_t;
typedef __attribute__((address_space(3))) void las_t;

__device__ __forceinline__ unsigned short f2bf(float f) {
    union { float f; unsigned u; } v; v.f = f;
    unsigned u = v.u;
    return (unsigned short)((u + 0x7fffu + ((u >> 16) & 1u)) >> 16);
}

__device__ __forceinline__ float gelu_f(float v) {
    return 0.5f * v * (1.0f + erff(v * 0.70710678118654752f));
}

// ---------------- W tile transpose-convert into TILE-BLOCKED layout ----------------
// Wt layout: [e][nb][kt][r][kk], nb=n/64, kt=k/64, r=n%64, kk=k%64 (4096 shorts/tile).
// Each block's output = ONE contiguous 8KB region (was 64 rows x 128B at 2KB stride):
// a wave's store instruction covers 1024B contiguous -- 8x the DRAM contiguity.
// GEMM reads are unchanged 128B row-chunks (tile row r is contiguous in kk).
template<int K, int NC>
__device__ __forceinline__ void cvt_tile(const float* __restrict__ W,
                                         unsigned short* __restrict__ Wt,
                                         int bx, int by, unsigned short* T) {
    constexpr int ktiles = K / 64;
    const int e  = by / ktiles;
    const int kt = by % ktiles;
    const int k0 = kt * 64;
    const int n0 = bx * 64;
    const float* src = W + (long)e * K * NC + (long)k0 * NC + n0;
    const int tid = threadIdx.x;
#pragma unroll
    for (int i = 0; i < 2; ++i) {
        const int idx = tid + i * 256;           // 0..511 over 32 row-pairs x 16 col-chunks
        const int kp = idx >> 4;                 // row pair 0..31
        const int c4 = (idx & 15) * 4;           // col 0..60
        const float4 v0 = *(const float4*)(src + (long)(2 * kp)     * NC + c4);
        const float4 v1 = *(const float4*)(src + (long)(2 * kp + 1) * NC + c4);
        *(ushort2*)&T[(c4 + 0) * 68 + 2 * kp] = make_ushort2(f2bf(v0.x), f2bf(v1.x));
        *(ushort2*)&T[(c4 + 1) * 68 + 2 * kp] = make_ushort2(f2bf(v0.y), f2bf(v1.y));
        *(ushort2*)&T[(c4 + 2) * 68 + 2 * kp] = make_ushort2(f2bf(v0.z), f2bf(v1.z));
        *(ushort2*)&T[(c4 + 3) * 68 + 2 * kp] = make_ushort2(f2bf(v0.w), f2bf(v1.w));
    }
    __syncthreads();
    unsigned short* dst = Wt + ((long)(e * (NC / 64) + bx) * ktiles + kt) * 4096;
#pragma unroll
    for (int i = 0; i < 2; ++i) {
        const int idx = tid + i * 256;           // 0..511 over 64 n-rows x 8 chunks
        const int n = idx >> 3, c8 = (idx & 7) * 8;
        union { ushort4 h[2]; int4 v; } u;
        u.h[0] = *(const ushort4*)&T[n * 68 + c8];
        u.h[1] = *(const ushort4*)&T[n * 68 + c8 + 4];
        *(int4*)(dst + n * 64 + c8) = u.v;       // contiguous 8KB per block
    }
}

// ---------------- gating: one wave per token (also emits xb = bf16(x)) ----------------
__global__ void k_gate(const float* __restrict__ x, const float* __restrict__ gw,
                       const float* __restrict__ gb, unsigned short* __restrict__ xb,
                       int* __restrict__ sel, int* __restrict__ counts) {
    const int wid = threadIdx.x >> 6, lane = threadIdx.x & 63;
    const int tok = blockIdx.x * 4 + wid;
    const float4* xr4 = (const float4*)(x + (long)tok * DDIM);
    unsigned short* xbr = xb + (long)tok * DDIM;
    float s[NEXP];
#pragma unroll
    for (int e = 0; e < NEXP; ++e) s[e] = 0.f;
#pragma unroll
    for (int it = 0; it < DDIM / 256; ++it) {
        const int q = it * 64 + lane;            // float4 index
        const float4 xv = xr4[q];
        *(ushort4*)(xbr + q * 4) = make_ushort4(f2bf(xv.x), f2bf(xv.y), f2bf(xv.z), f2bf(xv.w));
#pragma unroll
        for (int j = 0; j < 4; ++j) {
            const float xs = (j == 0) ? xv.x : (j == 1) ? xv.y : (j == 2) ? xv.z : xv.w;
            const float4* g4 = (const float4*)(gw + (long)(q * 4 + j) * NEXP);
            const float4 g0 = g4[0], g1 = g4[1];
            s[0] += xs * g0.x; s[1] += xs * g0.y; s[2] += xs * g0.z; s[3] += xs * g0.w;
            s[4] += xs * g1.x; s[5] += xs * g1.y; s[6] += xs * g1.z; s[7] += xs * g1.w;
        }
    }
#pragma unroll
    for (int e = 0; e < NEXP; ++e)
        for (int off = 32; off > 0; off >>= 1)
            s[e] += __shfl_down(s[e], off);
    if (lane == 0) {
        float best = s[0] + gb[0]; int bi = 0;
#pragma unroll
        for (int e = 1; e < NEXP; ++e) {
            const float v = s[e] + gb[e];
            if (v > best) { best = v; bi = e; }   // strict > keeps lowest index (np.argmax)
        }
        sel[tok] = bi;
        atomicAdd(&counts[bi], 1);
    }
}

// ---------------- fused: fill (blocks 0..NFILL-1, LDS-rank) + cvt(w1) behind ----------
__global__ __launch_bounds__(256) void k_fillcvt(
        const int* __restrict__ sel, const int* __restrict__ counts,
        int* __restrict__ cur, int* __restrict__ offs,
        int* __restrict__ list, int* __restrict__ t0,
        int* __restrict__ t1, float* __restrict__ laux,
        const float* __restrict__ w1, unsigned short* __restrict__ W1t) {
    __shared__ unsigned short T[64 * 68];
    __shared__ int hist[NEXP], basep[NEXP];
    const int bid = blockIdx.x;
    if (bid >= NFILL) {
        const int cv = bid - NFILL;
        cvt_tile<DDIM, HDIM>(w1, W1t, cv % (HDIM / 64), cv / (HDIM / 64), T);
        return;
    }
    const int tid = threadIdx.x;
    const int t = bid * 256 + tid;               // 16*256 == NTOK exactly
    const int e = sel[t];
    if (tid < NEXP) hist[tid] = 0;
    __syncthreads();
    const int rank = atomicAdd(&hist[e], 1);     // LDS atomic: block-local rank
    __syncthreads();
    if (tid < NEXP) {
        int off_e = 0;
#pragma unroll
        for (int j = 0; j < NEXP; ++j) off_e += (j < tid) ? counts[j] : 0;
        basep[tid] = off_e + atomicAdd(&cur[tid], hist[tid]);   // grab block's span
    }
    __syncthreads();
    list[basep[e] + rank] = t;
    if (t == 0) {
        int o = 0;
        for (int ee = 0; ee < NEXP; ++ee) { offs[ee] = o; o += counts[ee]; }
        offs[NEXP] = o;
        int i0 = 0;
        for (int ee = 0; ee < NEXP; ++ee)
            for (int m = 0; m < counts[ee]; m += 128) t0[i0++] = (ee << 16) | m;
        while (i0 < T0MAX) t0[i0++] = -1;
        int i1 = 0;
        for (int ee = 0; ee < NEXP; ++ee)
            for (int m = 0; m < counts[ee]; m += 64) t1[i1++] = (ee << 16) | m;
        while (i1 < T1MAX) t1[i1++] = -1;
        laux[0] = 0.f;
    }
}

// ---------------- standalone transpose-convert kernel (small-ws fallback) -------------
template<int K, int NC>
__global__ __launch_bounds__(256) void k_cvt_w(const float* __restrict__ W,
                                               unsigned short* __restrict__ Wt) {
    __shared__ unsigned short T[64 * 68];
    cvt_tile<K, NC>(W, Wt, blockIdx.x, blockIdx.y, T);
}

// ---------------- grouped GEMM: R5 single-buffer structure + compact grid -------------
// B reads from TILE-BLOCKED Wt: per-row base = ((e*NC/64+nb)*K/64)*4096 + rr*64, per
// k-tile stride 4096 shorts. Each staged chunk is the same 128B the row-major layout
// gave -- only the cvt's store contiguity changed. A side / LDS / MFMA untouched.
template<int MODE, int BM_, int BN_, bool FUSE>
__global__ __launch_bounds__(256) void k_gemm(
        const unsigned short* __restrict__ Ain,
        const unsigned short* __restrict__ Wt,
        const float* __restrict__ bias,
        unsigned short* __restrict__ Hout, float* __restrict__ Yout,
        const int* __restrict__ counts, const int* __restrict__ offs,
        const int* __restrict__ list, const int* __restrict__ ttab,
        const float* __restrict__ Wcvt, unsigned short* __restrict__ Wtcvt) {
    static_assert(BM_ % 32 == 0 && BN_ % 32 == 0, "tile");
    constexpr int K    = (MODE == 0) ? DDIM : HDIM;
    constexpr int NC   = (MODE == 0) ? HDIM : DDIM;
    constexpr int NT   = K / BK;
    constexpr int FM   = BM_ / 32;
    constexpr int FN   = BN_ / 32;
    constexpr int LA   = BM_ / 32;   // A loads per thread per tile
    constexpr int LB   = BN_ / 32;
    constexpr int EP   = 136;        // MODE0 epilogue stride (shorts), 16B-mult
    constexpr int STAGE_SH = BM_ * 64 + BN_ * 64;
    constexpr int SH_SZ = (MODE == 0 && BM_ * EP > STAGE_SH) ? BM_ * EP : STAGE_SH;

    __shared__ __align__(16) unsigned short sh[SH_SZ];

    int bx, by;
    if constexpr (FUSE) {
        const int bid = blockIdx.x;
        if (bid >= NG0) {                         // cvt_w2 block
            const int cv = bid - NG0;
            cvt_tile<HDIM, DDIM>(Wcvt, Wtcvt, cv % (DDIM / 64), cv / (DDIM / 64), sh);
            return;
        }
        bx = bid % (NC / BN_); by = bid / (NC / BN_);
    } else {
        bx = blockIdx.x; by = blockIdx.y;
    }

    const int code = ttab[by];
    if (code < 0) return;
    const int e  = code >> 16;
    const int m0 = code & 0xFFFF;
    const int cnt  = counts[e];
    const int base = offs[e];
    const int n0   = bx * BN_;

    unsigned short* Asb = sh;
    unsigned short* Btb = sh + BM_ * 64;

    const int tid  = threadIdx.x;
    const int lane = tid & 63, wid = tid >> 6;
    const int lr = lane >> 3, lc = lane & 7;
    const int sb = (lc * 16) ^ (lr << 4);        // pre-swizzled source byte offset

    const unsigned short* pA[LA];
#pragma unroll
    for (int i = 0; i < LA; ++i) {
        const int r = wid * (BM_ / 4) + i * 8 + lr;
        int rr = m0 + r; if (rr >= cnt) rr = cnt - 1;
        const long grow = (MODE == 0) ? (long)list[base + rr] : (long)(base + rr);
        pA[i] = (const unsigned short*)((const char*)(Ain + grow * K) + sb);
    }
    const unsigned short* pB[LB];
#pragma unroll
    for (int i = 0; i < LB; ++i) {
        const int r  = wid * (BN_ / 4) + i * 8 + lr;
        const int n  = n0 + r;                   // global output column
        const int nb = n >> 6, rr = n & 63;      // tile-blocked coords (rr&7 == lr)
        const long wbase = ((long)(e * (NC / 64) + nb) * (K / 64)) * 4096 + rr * 64;
        pB[i] = (const unsigned short*)((const char*)(Wt + wbase) + sb);
    }

    const int wm = (wid >> 1) * (BM_ / 2);
    const int wn = (wid & 1) * (BN_ / 2);
    const int hk = 16 * (lane >> 4);

    const f32x4 zero4 = {0.f, 0.f, 0.f, 0.f};
    f32x4 acc[FM][FN];
#pragma unroll
    for (int i = 0; i < FM; ++i)
#pragma unroll
        for (int j = 0; j < FN; ++j) acc[i][j] = zero4;

    for (int t = 0; t < NT; ++t) {
        __syncthreads();   // prior-iter readers done
#pragma unroll
        for (int i = 0; i < LA; ++i)
            __builtin_amdgcn_global_load_lds((gas_t*)(pA[i] + t * 64),
                (las_t*)(Asb + (wid * (BM_ / 4) + i * 8) * 64), 16, 0, 0);
#pragma unroll
        for (int i = 0; i < LB; ++i)
            __builtin_amdgcn_global_load_lds((gas_t*)(pB[i] + t * 4096),
                (las_t*)(Btb + (wid * (BN_ / 4) + i * 8) * 64), 16, 0, 0);
        __syncthreads();   // staging complete
#pragma unroll
        for (int kk = 0; kk < BK; kk += 32) {
            bf16x8 a[FM], b[FN];
#pragma unroll
            for (int mf = 0; mf < FM; ++mf) {
                const int r  = wm + mf * 16 + (lane & 15);
                const int kb = (2 * kk + hk) ^ ((r & 7) << 4);
                a[mf] = *(const bf16x8*)((const char*)Asb + r * 128 + kb);
            }
#pragma unroll
            for (int nf = 0; nf < FN; ++nf) {
                const int cc = wn + nf * 16 + (lane & 15);
                const int kb = (2 * kk + hk) ^ ((cc & 7) << 4);
                b[nf] = *(const bf16x8*)((const char*)Btb + cc * 128 + kb);
            }
            __builtin_amdgcn_s_setprio(1);
#pragma unroll
            for (int mf = 0; mf < FM; ++mf)
#pragma unroll
                for (int nf = 0; nf < FN; ++nf)
                    acc[mf][nf] = __builtin_amdgcn_mfma_f32_16x16x32_bf16(
                        a[mf], b[nf], acc[mf][nf], 0, 0, 0);
            __builtin_amdgcn_s_setprio(0);
        }
    }

    // ---- epilogue ----
    if constexpr (MODE == 0) {
        // bias+gelu -> bf16 tile in LDS ([BM][EP=136] shorts), 16B coalesced stores.
        __syncthreads();   // all MFMA reads of sh done
#pragma unroll
        for (int nf = 0; nf < FN; ++nf) {
            const int cl = wn + nf * 16 + (lane & 15);
            const float bv = bias[(long)e * NC + n0 + cl];
#pragma unroll
            for (int mf = 0; mf < FM; ++mf) {
#pragma unroll
                for (int ri = 0; ri < 4; ++ri) {
                    const int rl = wm + mf * 16 + (lane >> 4) * 4 + ri;
                    sh[rl * EP + cl] = f2bf(gelu_f(acc[mf][nf][ri] + bv));
                }
            }
        }
        __syncthreads();
        const int row = tid >> 1, ch = (tid & 1) * 64;
        if (m0 + row < cnt) {
            char* dst = (char*)(Hout + (long)(base + m0 + row) * HDIM + n0 + ch);
            const char* srcp = (const char*)sh + row * (EP * 2) + ch * 2;
#pragma unroll
            for (int j = 0; j < 4; ++j) {
                const int4 v0 = *(const int4*)(srcp + j * 32);
                const int4 v1 = *(const int4*)(srcp + j * 32 + 16);
                *(int4*)(dst + j * 32)      = v0;
                *(int4*)(dst + j * 32 + 16) = v1;
            }
        }
    } else {
#pragma unroll
        for (int nf = 0; nf < FN; ++nf) {
            const int coln = n0 + wn + nf * 16 + (lane & 15);
            const float bv = bias[(long)e * NC + coln];
#pragma unroll
            for (int mf = 0; mf < FM; ++mf) {
                const int rb = m0 + wm + mf * 16 + (lane >> 4) * 4;
#pragma unroll
                for (int ri = 0; ri < 4; ++ri) {
                    const int row = rb + ri;
                    if (row < cnt)
                        Yout[(long)list[base + row] * DDIM + coln] = acc[mf][nf][ri] + bv;
                }
            }
        }
    }
}

extern "C" void kernel_launch(void* const* d_in, const int* in_sizes, int n_in,
                              void* d_out, int out_size, void* d_ws, size_t ws_size,
                              hipStream_t stream) {
    const float* x      = (const float*)d_in[0];
    const float* gate_w = (const float*)d_in[1];
    const float* gate_b = (const float*)d_in[2];
    const float* w1     = (const float*)d_in[3];
    const float* b1     = (const float*)d_in[4];
    const float* w2     = (const float*)d_in[5];
    const float* b2     = (const float*)d_in[6];
    float* out = (float*)d_out;

    // workspace layout
    char* ws = (char*)d_ws;
    int* counts  = (int*)(ws);                 // 8
    int* cur     = (int*)(ws + 128);           // 8
    int* offs    = (int*)(ws + 256);           // 9
    int* t0      = (int*)(ws + 512);           // T0MAX
    int* t1      = (int*)(ws + 768);           // T1MAX
    int* sel     = (int*)(ws + 4096);          // 4096
    int* list    = (int*)(ws + 20480);         // 4096
    unsigned short* xb  = (unsigned short*)(ws + 65536);                      // 8 MB
    unsigned short* Hws = (unsigned short*)(ws + 65536 + 8388608);            // 33.5 MB
    unsigned short* W1t = (unsigned short*)(ws + 65536 + 8388608 + 33554432); // 64 MB
    unsigned short* W2s = W1t + (size_t)NEXP * HDIM * DDIM;                   // 64 MB (big path)
    const size_t WS_SMALL = 65536 + 8388608 + 33554432 + 67108864;
    const size_t WS_BIG   = WS_SMALL + 67108864;
    if (ws_size < WS_SMALL) return;  // deterministic fail, no corruption
    const bool big = ws_size >= WS_BIG;
    unsigned short* W2t = big ? W2s : W1t;     // small path reuses W1t region sequentially

    hipMemsetAsync(ws, 0, 256, stream);   // counts + cur

    // gate (+ xb): standalone (gate+cvt fusion measured 2x WORSE than sequential)
    k_gate<<<NTOK / 4, 256, 0, stream>>>(x, gate_w, gate_b, xb, sel, counts);

    // fill (16 LDS-rank blocks) fused ahead of cvt(w1) -> W1t (tile-blocked)
    k_fillcvt<<<NFILL + NCVT1, 256, 0, stream>>>(sel, counts, cur, offs, list, t0, t1,
                                                 out + (long)NTOK * DDIM, w1, W1t);

    if (big) {
        // FFN up+gelu FUSED with cvt(w2)->W2t: gemm blocks 0..NG0-1, cvt blocks behind
        k_gemm<0, 128, 128, true><<<NG0 + NCVT2, 256, 0, stream>>>(
            xb, W1t, b1, Hws, nullptr, counts, offs, list, t0, w2, W2t);
    } else {
        k_gemm<0, 128, 128, false><<<dim3(HDIM / 128, T0MAX), 256, 0, stream>>>(
            xb, W1t, b1, Hws, nullptr, counts, offs, list, t0, nullptr, nullptr);
        k_cvt_w<HDIM, DDIM><<<dim3(DDIM / 64, NEXP * (HDIM / 64)), 256, 0, stream>>>(w2, W2t);
    }

    // FFN down: 64x128 tiles (best-measured GEMM1), compact grid
    k_gemm<1, 64, 128, false><<<dim3(DDIM / 128, T1MAX), 256, 0, stream>>>(
        Hws, W2t, b2, nullptr, out, counts, offs, list, t1, nullptr, nullptr);
}

// Round 19
// 246.809 us; speedup vs baseline: 1.0546x; 1.0126x over previous
//
#include <hip/hip_runtime.h>
#include <math.h>

#define NTOK 4096
#define DDIM 1024
#define HDIM 4096
#define NEXP 8
#define BK 64
#define T0MAX 40   // >= NTOK/128 + NEXP-1 live tiles for GEMM0
#define T1MAX 72   // >= NTOK/64  + NEXP-1 live tiles for GEMM1
#define NFILL (NTOK / 256)                            // 16 fill blocks
#define NCVT1 ((HDIM / 64) * (NEXP * (DDIM / 64)))    // 8192 cvt_w1 blocks
#define NG0   ((HDIM / 128) * T0MAX)                  // 1280 gemm0 blocks
#define NCVT2 ((DDIM / 64) * (NEXP * (HDIM / 64)))    // 8192 cvt_w2 blocks

typedef float f32x4 __attribute__((ext_vector_type(4)));
typedef __bf16 bf16x8 __attribute__((ext_vector_type(8)));
typedef const __attribute__((address_space(1))) void gas_t;
typedef __attribute__((address_space(3))) void las_t;

__device__ __forceinline__ unsigned short f2bf(float f) {
    union { float f; unsigned u; } v; v.f = f;
    unsigned u = v.u;
    return (unsigned short)((u + 0x7fffu + ((u >> 16) & 1u)) >> 16);
}

__device__ __forceinline__ float gelu_f(float v) {
    return 0.5f * v * (1.0f + erff(v * 0.70710678118654752f));
}

// ---------------- W tile transpose-convert into TILE-BLOCKED layout ----------------
// Wt layout: [e][nb][kt][r][kk], nb=n/64, kt=k/64, r=n%64, kk=k%64 (4096 shorts/tile).
// Each block's output = ONE contiguous 8KB region; GEMM reads unchanged 128B chunks.
template<int K, int NC>
__device__ __forceinline__ void cvt_tile(const float* __restrict__ W,
                                         unsigned short* __restrict__ Wt,
                                         int bx, int by, unsigned short* T) {
    constexpr int ktiles = K / 64;
    const int e  = by / ktiles;
    const int kt = by % ktiles;
    const int k0 = kt * 64;
    const int n0 = bx * 64;
    const float* src = W + (long)e * K * NC + (long)k0 * NC + n0;
    const int tid = threadIdx.x;
#pragma unroll
    for (int i = 0; i < 2; ++i) {
        const int idx = tid + i * 256;           // 0..511 over 32 row-pairs x 16 col-chunks
        const int kp = idx >> 4;                 // row pair 0..31
        const int c4 = (idx & 15) * 4;           // col 0..60
        const float4 v0 = *(const float4*)(src + (long)(2 * kp)     * NC + c4);
        const float4 v1 = *(const float4*)(src + (long)(2 * kp + 1) * NC + c4);
        *(ushort2*)&T[(c4 + 0) * 68 + 2 * kp] = make_ushort2(f2bf(v0.x), f2bf(v1.x));
        *(ushort2*)&T[(c4 + 1) * 68 + 2 * kp] = make_ushort2(f2bf(v0.y), f2bf(v1.y));
        *(ushort2*)&T[(c4 + 2) * 68 + 2 * kp] = make_ushort2(f2bf(v0.z), f2bf(v1.z));
        *(ushort2*)&T[(c4 + 3) * 68 + 2 * kp] = make_ushort2(f2bf(v0.w), f2bf(v1.w));
    }
    __syncthreads();
    unsigned short* dst = Wt + ((long)(e * (NC / 64) + bx) * ktiles + kt) * 4096;
#pragma unroll
    for (int i = 0; i < 2; ++i) {
        const int idx = tid + i * 256;           // 0..511 over 64 n-rows x 8 chunks
        const int n = idx >> 3, c8 = (idx & 7) * 8;
        union { ushort4 h[2]; int4 v; } u;
        u.h[0] = *(const ushort4*)&T[n * 68 + c8];
        u.h[1] = *(const ushort4*)&T[n * 68 + c8 + 4];
        *(int4*)(dst + n * 64 + c8) = u.v;       // contiguous 8KB per block
    }
}

// ---------------- gating: one wave per token (also emits xb = bf16(x)) ----------------
__global__ void k_gate(const float* __restrict__ x, const float* __restrict__ gw,
                       const float* __restrict__ gb, unsigned short* __restrict__ xb,
                       int* __restrict__ sel, int* __restrict__ counts) {
    const int wid = threadIdx.x >> 6, lane = threadIdx.x & 63;
    const int tok = blockIdx.x * 4 + wid;
    const float4* xr4 = (const float4*)(x + (long)tok * DDIM);
    unsigned short* xbr = xb + (long)tok * DDIM;
    float s[NEXP];
#pragma unroll
    for (int e = 0; e < NEXP; ++e) s[e] = 0.f;
#pragma unroll
    for (int it = 0; it < DDIM / 256; ++it) {
        const int q = it * 64 + lane;            // float4 index
        const float4 xv = xr4[q];
        *(ushort4*)(xbr + q * 4) = make_ushort4(f2bf(xv.x), f2bf(xv.y), f2bf(xv.z), f2bf(xv.w));
#pragma unroll
        for (int j = 0; j < 4; ++j) {
            const float xs = (j == 0) ? xv.x : (j == 1) ? xv.y : (j == 2) ? xv.z : xv.w;
            const float4* g4 = (const float4*)(gw + (long)(q * 4 + j) * NEXP);
            const float4 g0 = g4[0], g1 = g4[1];
            s[0] += xs * g0.x; s[1] += xs * g0.y; s[2] += xs * g0.z; s[3] += xs * g0.w;
            s[4] += xs * g1.x; s[5] += xs * g1.y; s[6] += xs * g1.z; s[7] += xs * g1.w;
        }
    }
#pragma unroll
    for (int e = 0; e < NEXP; ++e)
        for (int off = 32; off > 0; off >>= 1)
            s[e] += __shfl_down(s[e], off);
    if (lane == 0) {
        float best = s[0] + gb[0]; int bi = 0;
#pragma unroll
        for (int e = 1; e < NEXP; ++e) {
            const float v = s[e] + gb[e];
            if (v > best) { best = v; bi = e; }   // strict > keeps lowest index (np.argmax)
        }
        sel[tok] = bi;
        atomicAdd(&counts[bi], 1);
    }
}

// ---------------- fused: fill (blocks 0..NFILL-1, LDS-rank) + cvt(w1) behind ----------
__global__ __launch_bounds__(256) void k_fillcvt(
        const int* __restrict__ sel, const int* __restrict__ counts,
        int* __restrict__ cur, int* __restrict__ offs,
        int* __restrict__ list, int* __restrict__ t0,
        int* __restrict__ t1, float* __restrict__ laux,
        const float* __restrict__ w1, unsigned short* __restrict__ W1t) {
    __shared__ unsigned short T[64 * 68];
    __shared__ int hist[NEXP], basep[NEXP];
    const int bid = blockIdx.x;
    if (bid >= NFILL) {
        const int cv = bid - NFILL;
        cvt_tile<DDIM, HDIM>(w1, W1t, cv % (HDIM / 64), cv / (HDIM / 64), T);
        return;
    }
    const int tid = threadIdx.x;
    const int t = bid * 256 + tid;               // 16*256 == NTOK exactly
    const int e = sel[t];
    if (tid < NEXP) hist[tid] = 0;
    __syncthreads();
    const int rank = atomicAdd(&hist[e], 1);     // LDS atomic: block-local rank
    __syncthreads();
    if (tid < NEXP) {
        int off_e = 0;
#pragma unroll
        for (int j = 0; j < NEXP; ++j) off_e += (j < tid) ? counts[j] : 0;
        basep[tid] = off_e + atomicAdd(&cur[tid], hist[tid]);   // grab block's span
    }
    __syncthreads();
    list[basep[e] + rank] = t;
    if (t == 0) {
        int o = 0;
        for (int ee = 0; ee < NEXP; ++ee) { offs[ee] = o; o += counts[ee]; }
        offs[NEXP] = o;
        int i0 = 0;
        for (int ee = 0; ee < NEXP; ++ee)
            for (int m = 0; m < counts[ee]; m += 128) t0[i0++] = (ee << 16) | m;
        while (i0 < T0MAX) t0[i0++] = -1;
        int i1 = 0;
        for (int ee = 0; ee < NEXP; ++ee)
            for (int m = 0; m < counts[ee]; m += 64) t1[i1++] = (ee << 16) | m;
        while (i1 < T1MAX) t1[i1++] = -1;
        laux[0] = 0.f;
    }
}

// ---------------- standalone transpose-convert kernel (small-ws fallback) -------------
template<int K, int NC>
__global__ __launch_bounds__(256) void k_cvt_w(const float* __restrict__ W,
                                               unsigned short* __restrict__ Wt) {
    __shared__ unsigned short T[64 * 68];
    cvt_tile<K, NC>(W, Wt, blockIdx.x, blockIdx.y, T);
}

// ---------------- grouped GEMM: R5 single-buffer structure + compact grid -------------
// B reads from TILE-BLOCKED Wt: per-row base = ((e*NC/64+nb)*K/64)*4096 + rr*64, per
// k-tile stride 4096 shorts. FUSE adds cvt_w2 guest blocks (compute-host + BW-guest,
// the verified-good fusion; flag-based sync measured 6x WORSE in R13 -- never again).
template<int MODE, int BM_, int BN_, bool FUSE>
__global__ __launch_bounds__(256) void k_gemm(
        const unsigned short* __restrict__ Ain,
        const unsigned short* __restrict__ Wt,
        const float* __restrict__ bias,
        unsigned short* __restrict__ Hout, float* __restrict__ Yout,
        const int* __restrict__ counts, const int* __restrict__ offs,
        const int* __restrict__ list, const int* __restrict__ ttab,
        const float* __restrict__ Wcvt, unsigned short* __restrict__ Wtcvt) {
    static_assert(BM_ % 32 == 0 && BN_ % 32 == 0, "tile");
    constexpr int K    = (MODE == 0) ? DDIM : HDIM;
    constexpr int NC   = (MODE == 0) ? HDIM : DDIM;
    constexpr int NT   = K / BK;
    constexpr int FM   = BM_ / 32;
    constexpr int FN   = BN_ / 32;
    constexpr int LA   = BM_ / 32;   // A loads per thread per tile
    constexpr int LB   = BN_ / 32;
    constexpr int EP   = 136;        // MODE0 epilogue stride (shorts), 16B-mult
    constexpr int STAGE_SH = BM_ * 64 + BN_ * 64;
    constexpr int SH_SZ = (MODE == 0 && BM_ * EP > STAGE_SH) ? BM_ * EP : STAGE_SH;

    __shared__ __align__(16) unsigned short sh[SH_SZ];

    int bx, by;
    if constexpr (FUSE) {
        const int bid = blockIdx.x;
        if (bid >= NG0) {                         // cvt_w2 block
            const int cv = bid - NG0;
            cvt_tile<HDIM, DDIM>(Wcvt, Wtcvt, cv % (DDIM / 64), cv / (DDIM / 64), sh);
            return;
        }
        bx = bid % (NC / BN_); by = bid / (NC / BN_);
    } else {
        bx = blockIdx.x; by = blockIdx.y;
    }

    const int code = ttab[by];
    if (code < 0) return;
    const int e  = code >> 16;
    const int m0 = code & 0xFFFF;
    const int cnt  = counts[e];
    const int base = offs[e];
    const int n0   = bx * BN_;

    unsigned short* Asb = sh;
    unsigned short* Btb = sh + BM_ * 64;

    const int tid  = threadIdx.x;
    const int lane = tid & 63, wid = tid >> 6;
    const int lr = lane >> 3, lc = lane & 7;
    const int sb = (lc * 16) ^ (lr << 4);        // pre-swizzled source byte offset

    const unsigned short* pA[LA];
#pragma unroll
    for (int i = 0; i < LA; ++i) {
        const int r = wid * (BM_ / 4) + i * 8 + lr;
        int rr = m0 + r; if (rr >= cnt) rr = cnt - 1;
        const long grow = (MODE == 0) ? (long)list[base + rr] : (long)(base + rr);
        pA[i] = (const unsigned short*)((const char*)(Ain + grow * K) + sb);
    }
    const unsigned short* pB[LB];
#pragma unroll
    for (int i = 0; i < LB; ++i) {
        const int r  = wid * (BN_ / 4) + i * 8 + lr;
        const int n  = n0 + r;                   // global output column
        const int nb = n >> 6, rr = n & 63;      // tile-blocked coords (rr&7 == lr)
        const long wbase = ((long)(e * (NC / 64) + nb) * (K / 64)) * 4096 + rr * 64;
        pB[i] = (const unsigned short*)((const char*)(Wt + wbase) + sb);
    }

    const int wm = (wid >> 1) * (BM_ / 2);
    const int wn = (wid & 1) * (BN_ / 2);
    const int hk = 16 * (lane >> 4);

    const f32x4 zero4 = {0.f, 0.f, 0.f, 0.f};
    f32x4 acc[FM][FN];
#pragma unroll
    for (int i = 0; i < FM; ++i)
#pragma unroll
        for (int j = 0; j < FN; ++j) acc[i][j] = zero4;

    for (int t = 0; t < NT; ++t) {
        __syncthreads();   // prior-iter readers done
#pragma unroll
        for (int i = 0; i < LA; ++i)
            __builtin_amdgcn_global_load_lds((gas_t*)(pA[i] + t * 64),
                (las_t*)(Asb + (wid * (BM_ / 4) + i * 8) * 64), 16, 0, 0);
#pragma unroll
        for (int i = 0; i < LB; ++i)
            __builtin_amdgcn_global_load_lds((gas_t*)(pB[i] + t * 4096),
                (las_t*)(Btb + (wid * (BN_ / 4) + i * 8) * 64), 16, 0, 0);
        __syncthreads();   // staging complete
#pragma unroll
        for (int kk = 0; kk < BK; kk += 32) {
            bf16x8 a[FM], b[FN];
#pragma unroll
            for (int mf = 0; mf < FM; ++mf) {
                const int r  = wm + mf * 16 + (lane & 15);
                const int kb = (2 * kk + hk) ^ ((r & 7) << 4);
                a[mf] = *(const bf16x8*)((const char*)Asb + r * 128 + kb);
            }
#pragma unroll
            for (int nf = 0; nf < FN; ++nf) {
                const int cc = wn + nf * 16 + (lane & 15);
                const int kb = (2 * kk + hk) ^ ((cc & 7) << 4);
                b[nf] = *(const bf16x8*)((const char*)Btb + cc * 128 + kb);
            }
            __builtin_amdgcn_s_setprio(1);
#pragma unroll
            for (int mf = 0; mf < FM; ++mf)
#pragma unroll
                for (int nf = 0; nf < FN; ++nf)
                    acc[mf][nf] = __builtin_amdgcn_mfma_f32_16x16x32_bf16(
                        a[mf], b[nf], acc[mf][nf], 0, 0, 0);
            __builtin_amdgcn_s_setprio(0);
        }
    }

    // ---- epilogue ----
    if constexpr (MODE == 0) {
        // bias+gelu -> bf16 tile in LDS ([BM][EP=136] shorts), 16B coalesced stores.
        __syncthreads();   // all MFMA reads of sh done
#pragma unroll
        for (int nf = 0; nf < FN; ++nf) {
            const int cl = wn + nf * 16 + (lane & 15);
            const float bv = bias[(long)e * NC + n0 + cl];
#pragma unroll
            for (int mf = 0; mf < FM; ++mf) {
#pragma unroll
                for (int ri = 0; ri < 4; ++ri) {
                    const int rl = wm + mf * 16 + (lane >> 4) * 4 + ri;
                    sh[rl * EP + cl] = f2bf(gelu_f(acc[mf][nf][ri] + bv));
                }
            }
        }
        __syncthreads();
        const int row = tid >> 1, ch = (tid & 1) * 64;
        if (m0 + row < cnt) {
            char* dst = (char*)(Hout + (long)(base + m0 + row) * HDIM + n0 + ch);
            const char* srcp = (const char*)sh + row * (EP * 2) + ch * 2;
#pragma unroll
            for (int j = 0; j < 4; ++j) {
                const int4 v0 = *(const int4*)(srcp + j * 32);
                const int4 v1 = *(const int4*)(srcp + j * 32 + 16);
                *(int4*)(dst + j * 32)      = v0;
                *(int4*)(dst + j * 32 + 16) = v1;
            }
        }
    } else {
#pragma unroll
        for (int nf = 0; nf < FN; ++nf) {
            const int coln = n0 + wn + nf * 16 + (lane & 15);
            const float bv = bias[(long)e * NC + coln];
#pragma unroll
            for (int mf = 0; mf < FM; ++mf) {
                const int rb = m0 + wm + mf * 16 + (lane >> 4) * 4;
#pragma unroll
                for (int ri = 0; ri < 4; ++ri) {
                    const int row = rb + ri;
                    if (row < cnt)
                        Yout[(long)list[base + row] * DDIM + coln] = acc[mf][nf][ri] + bv;
                }
            }
        }
    }
}

extern "C" void kernel_launch(void* const* d_in, const int* in_sizes, int n_in,
                              void* d_out, int out_size, void* d_ws, size_t ws_size,
                              hipStream_t stream) {
    const float* x      = (const float*)d_in[0];
    const float* gate_w = (const float*)d_in[1];
    const float* gate_b = (const float*)d_in[2];
    const float* w1     = (const float*)d_in[3];
    const float* b1     = (const float*)d_in[4];
    const float* w2     = (const float*)d_in[5];
    const float* b2     = (const float*)d_in[6];
    float* out = (float*)d_out;

    // workspace layout
    char* ws = (char*)d_ws;
    int* counts  = (int*)(ws);                 // 8
    int* cur     = (int*)(ws + 128);           // 8
    int* offs    = (int*)(ws + 256);           // 9
    int* t0      = (int*)(ws + 512);           // T0MAX
    int* t1      = (int*)(ws + 768);           // T1MAX
    int* sel     = (int*)(ws + 4096);          // 4096
    int* list    = (int*)(ws + 20480);         // 4096
    unsigned short* xb  = (unsigned short*)(ws + 65536);                      // 8 MB
    unsigned short* Hws = (unsigned short*)(ws + 65536 + 8388608);            // 33.5 MB
    unsigned short* W1t = (unsigned short*)(ws + 65536 + 8388608 + 33554432); // 64 MB
    unsigned short* W2s = W1t + (size_t)NEXP * HDIM * DDIM;                   // 64 MB (big path)
    const size_t WS_SMALL = 65536 + 8388608 + 33554432 + 67108864;
    const size_t WS_BIG   = WS_SMALL + 67108864;
    if (ws_size < WS_SMALL) return;  // deterministic fail, no corruption
    const bool big = ws_size >= WS_BIG;
    unsigned short* W2t = big ? W2s : W1t;     // small path reuses W1t region sequentially

    hipMemsetAsync(ws, 0, 256, stream);   // counts + cur

    // gate (+ xb): standalone (gate+cvt fusion measured 2x WORSE than sequential)
    k_gate<<<NTOK / 4, 256, 0, stream>>>(x, gate_w, gate_b, xb, sel, counts);

    // fill (16 LDS-rank blocks) fused ahead of cvt(w1) -> W1t (tile-blocked)
    k_fillcvt<<<NFILL + NCVT1, 256, 0, stream>>>(sel, counts, cur, offs, list, t0, t1,
                                                 out + (long)NTOK * DDIM, w1, W1t);

    if (big) {
        // FFN up+gelu FUSED with cvt(w2)->W2t: gemm blocks 0..NG0-1, cvt blocks behind
        k_gemm<0, 128, 128, true><<<NG0 + NCVT2, 256, 0, stream>>>(
            xb, W1t, b1, Hws, nullptr, counts, offs, list, t0, w2, W2t);
    } else {
        k_gemm<0, 128, 128, false><<<dim3(HDIM / 128, T0MAX), 256, 0, stream>>>(
            xb, W1t, b1, Hws, nullptr, counts, offs, list, t0, nullptr, nullptr);
        k_cvt_w<HDIM, DDIM><<<dim3(DDIM / 64, NEXP * (HDIM / 64)), 256, 0, stream>>>(w2, W2t);
    }

    // FFN down: 64x128 tiles (best-measured GEMM1), compact grid
    k_gemm<1, 64, 128, false><<<dim3(DDIM / 128, T1MAX), 256, 0, stream>>>(
        Hws, W2t, b2, nullptr, out, counts, offs, list, t1, nullptr, nullptr);
}